// Round 1
// 72.862 us; speedup vs baseline: 1.1495x; 1.1495x over previous
//
#include <hip/hip_runtime.h>

// RadiusInteractionGraph — f32 in, f32 out; reference compared in bf16.
// Semantics carried over unchanged from the harness-verified kernel
// (absmax==0.0): pad row=0, col=i always, pad w=0, pad mask=0; self-loop
// row=col=i, w=0, mask=1; all emitted values bf16-rounded (RNE) then
// expanded to f32. d2 pipeline mirrors np gram-trick op order exactly.
//
// R7 restructure (perf only, math identical):
//  * wave-per-center: 2048 blocks x 256 thr -> 8192 waves = exactly one
//    full-occupancy round (was 32768 waves = 4 rounds with <15% lane use
//    in the rank phase).
//  * segment bounds [bounds[g], bounds[g+1]) precomputed by a tiny
//    prologue kernel into a __device__ array — removes the redundant
//    13-step dependent-load binary search from every block.
//  * ballot-prefix candidate compaction (no LDS atomics, deterministic
//    j-ascending order; rank result unaffected — rank is a full compare).
//  * candidates packed as float2 {d2, idx} -> rank inner loop is one
//    broadcast ds_read_b64 per q.

#define NPTS 8192
#define KNN 32
#define NG 8
#define MAXC 192
#define EDGES (NPTS * KNN + NPTS)   // 270336

__device__ int g_bounds[NG + 1];    // bounds[g] = first idx with batch >= g

__device__ __forceinline__ float bfq(float f) {
    // quantize f32 -> bf16 grid (RNE), return as f32
    union { float f; unsigned int i; } v;
    v.f = f;
    unsigned int b = v.i;
    unsigned int r = (b + 0x7FFFu + ((b >> 16) & 1u)) & 0xFFFF0000u;
    v.i = r;
    return v.f;
}

// batch storage detection: int32 -> word[N-1] = last batch id = NG-1;
// int64 -> word[N-1] is the HIGH word of element N/2-1 = 0.
__device__ __forceinline__ int batch_stride(const int* __restrict__ b) {
    return (b[NPTS - 1] != NG - 1) ? 2 : 1;
}

__global__ __launch_bounds__(256) void bounds_kernel(
        const int* __restrict__ batch32) {
    const int tid = blockIdx.x * 256 + threadIdx.x;
    if (tid >= NPTS) return;
    const int stride = batch_stride(batch32);
    const int g  = batch32[tid * stride];
    const int gp = (tid == 0) ? -1 : batch32[(tid - 1) * stride];
    for (int v = gp + 1; v <= g; ++v) g_bounds[v] = tid;
    if (tid == NPTS - 1) {
        for (int v = g + 1; v <= NG; ++v) g_bounds[v] = NPTS;
    }
}

__global__ __launch_bounds__(256) void radius_graph_kernel(
        const float* __restrict__ pos,       // f32 [N,3]
        const int*   __restrict__ batch32,   // int32 (or int64 low/high words)
        float*       __restrict__ out) {     // f32 [4E]
    const int wave = threadIdx.x >> 6;
    const int lane = threadIdx.x & 63;
    const int i = (blockIdx.x << 2) + wave;  // center node (one wave each)

    __shared__ float2 s_cand[4][MAXC];       // {d2, idx-as-float-bits}

    const int stride = batch_stride(batch32);
    const int g = batch32[i * stride];
    const int s = g_bounds[g];
    const int e = g_bounds[g + 1];

    // |p_i|^2 in np order: (x*x + y*y) + z*z, each op separately rounded.
    const float xi = pos[3 * i + 0];
    const float yi = pos[3 * i + 1];
    const float zi = pos[3 * i + 2];
    const float x2i = __fadd_rn(__fadd_rn(__fmul_rn(xi, xi), __fmul_rn(yi, yi)),
                                __fmul_rn(zi, zi));

    // scan own batch segment; ballot-prefix compaction into wave-private LDS
    int cnt = 0;
    for (int j0 = s; j0 < e; j0 += 64) {
        const int j = j0 + lane;
        bool ok = false;
        float d2 = 0.0f;
        if (j < e && j != i) {
            const float xj = pos[3 * j + 0];
            const float yj = pos[3 * j + 1];
            const float zj = pos[3 * j + 2];
            const float x2j = __fadd_rn(
                __fadd_rn(__fmul_rn(xj, xj), __fmul_rn(yj, yj)),
                __fmul_rn(zj, zj));
            // dot: ascending-k FMA chain (== mul+add chain when products exact)
            float dot = __fmul_rn(xi, xj);
            dot = __fmaf_rn(yi, yj, dot);
            dot = __fmaf_rn(zi, zj, dot);
            // d2 = (x2i + x2j) - 2*dot, np gram-trick expression order
            d2 = __fsub_rn(__fadd_rn(x2i, x2j), __fmul_rn(2.0f, dot));
            ok = (d2 <= 100.0f);
        }
        const unsigned long long m = __ballot(ok);
        if (ok) {
            const int p = cnt + __popcll(m & ((1ull << lane) - 1ull));
            if (p < MAXC) s_cand[wave][p] = make_float2(d2, __int_as_float(j));
        }
        cnt += (int)__popcll(m);
    }
    cnt = min(cnt, MAXC);
    __syncthreads();   // orders LDS writes before reads (also inter-wave safe)

    const int E = EDGES;
    const float fci = bfq((float)i);     // bf16-grid center index
    const int ne = min(cnt, KNN);

    // exact rank of candidate c: ascending d2, ties -> lower index first
    // (matches jax.lax.top_k stable tie behavior)
    for (int c = lane; c < cnt; c += 64) {
        const float2 pc = s_cand[wave][c];
        const float dc = pc.x;
        const int   ic = __float_as_int(pc.y);
        int rank = 0;
        for (int q = 0; q < cnt; ++q) {
            const float2 pq = s_cand[wave][q];    // broadcast ds_read_b64
            const float dq = pq.x;
            if (dq < dc || (dq == dc && __float_as_int(pq.y) < ic)) rank++;
        }
        if (rank < KNN) {
            const int slot = i * KNN + rank;
            // weight = ||pos[row]-pos[col]||, np order
            const float dx = __fsub_rn(pos[3 * ic + 0], xi);
            const float dy = __fsub_rn(pos[3 * ic + 1], yi);
            const float dz = __fsub_rn(pos[3 * ic + 2], zi);
            const float sq = __fadd_rn(
                __fadd_rn(__fmul_rn(dx, dx), __fmul_rn(dy, dy)),
                __fmul_rn(dz, dz));
            const float w = (sq > 0.0f) ? __fsqrt_rn(sq) : 0.0f;
            out[slot]         = bfq((float)ic);  // row = neighbor (source)
            out[E + slot]     = fci;             // col = center (target)
            out[2 * E + slot] = bfq(w);          // weight
            out[3 * E + slot] = 1.0f;            // mask
        }
    }
    // padded slots: row=0 (where(mask,row,0)), col=i, weight=0, mask=0
    for (int c = ne + lane; c < KNN; c += 64) {
        const int slot = i * KNN + c;
        out[slot]         = 0.0f;
        out[E + slot]     = fci;
        out[2 * E + slot] = 0.0f;
        out[3 * E + slot] = 0.0f;
    }
    // self-loop appended at end: row=col=i, weight 0, mask 1
    if (lane == 0) {
        const int slot = NPTS * KNN + i;
        out[slot]         = fci;
        out[E + slot]     = fci;
        out[2 * E + slot] = 0.0f;
        out[3 * E + slot] = 1.0f;
    }
}

extern "C" void kernel_launch(void* const* d_in, const int* in_sizes, int n_in,
                              void* d_out, int out_size, void* d_ws, size_t ws_size,
                              hipStream_t stream) {
    const float* pos   = (const float*)d_in[0];   // f32 [N,3]
    const int* batch32 = (const int*)d_in[1];     // int32 (int64 tolerated)
    float* out = (float*)d_out;                   // f32 [4E]

    bounds_kernel<<<32, 256, 0, stream>>>(batch32);
    radius_graph_kernel<<<2048, 256, 0, stream>>>(pos, batch32, out);
}